// Round 17
// baseline (733.134 us; speedup 1.0000x reference)
//
#include <hip/hip_runtime.h>
#include <hip/hip_bf16.h>
#include <math.h>

typedef __bf16 bf16x8 __attribute__((ext_vector_type(8)));
typedef float f32x4 __attribute__((ext_vector_type(4)));
typedef _Float16 h16x2 __attribute__((ext_vector_type(2)));

#define LOG2F 0.6931471805599453f
#define PK1 72     // padded row length (bf16) for K=64 tiles
#define PK2 136    // padded row length (bf16) for K=128 tiles

__device__ __forceinline__ float sspf(float x) {
    float t = __expf(-fabsf(x));
    return fmaxf(x, 0.0f) + __logf(1.0f + t) - LOG2F;
}
__device__ __forceinline__ unsigned short f2bf(float f) {
    union { float f; unsigned u; } v; v.f = f;
    unsigned r = v.u + 0x7FFF + ((v.u >> 16) & 1);
    return (unsigned short)(r >> 16);
}
__device__ __forceinline__ float bf2f(unsigned short u) {
    union { unsigned u; float f; } v; v.u = ((unsigned)u) << 16;
    return v.f;
}
__device__ __forceinline__ unsigned short f2bf_fast(float f) {
    __bf16 h = (__bf16)f;
    return __builtin_bit_cast(unsigned short, h);
}

// ---------------- all weight pre-converts in one kernel ----------------
__global__ void convert_all(
    const float* __restrict__ A0, const float* __restrict__ A1,
    const float* __restrict__ A2, const float* __restrict__ A3,
    const float* __restrict__ A4, const float* __restrict__ A5,
    const float* __restrict__ A6, const float* __restrict__ A7,
    unsigned short* __restrict__ O0, unsigned short* __restrict__ O1,
    unsigned short* __restrict__ O2, unsigned short* __restrict__ O3,
    unsigned short* __restrict__ H4, unsigned short* __restrict__ L4,
    unsigned short* __restrict__ H5, unsigned short* __restrict__ L5,
    unsigned short* __restrict__ H6, unsigned short* __restrict__ L6,
    unsigned short* __restrict__ H7, unsigned short* __restrict__ L7)
{
    const int seg = blockIdx.x / 68;
    const int idx = (blockIdx.x % 68) * 256 + threadIdx.x;
    if (seg < 4) {
        const int PK = (seg == 0 || seg == 2) ? PK1 : PK2;
        const int K  = (seg == 0 || seg == 2) ? 64 : 128;
        if (idx >= 128 * PK) return;
        const float* W = (seg == 0) ? A0 : (seg == 1) ? A1 : (seg == 2) ? A2 : A3;
        unsigned short* O = (seg == 0) ? O0 : (seg == 1) ? O1 : (seg == 2) ? O2 : O3;
        int n = idx / PK, k = idx - n * PK;
        O[idx] = (k < K) ? f2bf(W[k * 128 + n]) : (unsigned short)0;
    } else {
        if (idx >= 128 * PK2) return;
        const float* W = (seg == 4) ? A4 : (seg == 5) ? A5 : (seg == 6) ? A6 : A7;
        unsigned short* H = (seg == 4) ? H4 : (seg == 5) ? H5 : (seg == 6) ? H6 : H7;
        unsigned short* L = (seg == 4) ? L4 : (seg == 5) ? L5 : (seg == 6) ? L6 : L7;
        int n = idx / PK2, k = idx - n * PK2;
        unsigned short h = 0, lo = 0;
        if (k < 128) {
            float w = W[k * 128 + n];
            h = f2bf(w);
            lo = f2bf(w - bf2f(h));
        }
        H[idx] = h; L[idx] = lo;
    }
}

// ---------------- deterministic counting sort by dst ----------------
__global__ void hist_kernel(const int* __restrict__ dst, int* __restrict__ hist, int E) {
    int i = blockIdx.x * 256 + threadIdx.x;
    if (i < E) atomicAdd(&hist[dst[i]], 1);
}
__global__ void scan_kernel(const int* __restrict__ hist, int* __restrict__ row_ptr,
                            int* __restrict__ cursor, int N) {
    __shared__ int part[1024];
    const int tid = threadIdx.x;
    const int chunk = (N + 1023) / 1024;
    const int lo = min(tid * chunk, N);
    const int hi = min(lo + chunk, N);
    int s = 0;
    for (int i = lo; i < hi; ++i) s += hist[i];
    part[tid] = s;
    __syncthreads();
    for (int d = 1; d < 1024; d <<= 1) {
        int t = (tid >= d) ? part[tid - d] : 0;
        __syncthreads();
        part[tid] += t;
        __syncthreads();
    }
    int run = part[tid] - s;
    for (int i = lo; i < hi; ++i) { row_ptr[i] = run; cursor[i] = run; run += hist[i]; }
}
__global__ void scatter_kernel(const int* __restrict__ dst, int* __restrict__ cursor,
                               int* __restrict__ perm, int E) {
    int i = blockIdx.x * 256 + threadIdx.x;
    if (i < E) { int p = atomicAdd(&cursor[dst[i]], 1); perm[p] = i; }
}
__global__ void sort_buckets(const int* __restrict__ row_ptr, const int* __restrict__ hist,
                             int* __restrict__ perm, int N) {
    int n = blockIdx.x * 256 + threadIdx.x;
    if (n >= N) return;
    const int lo = row_ptr[n], hi = lo + hist[n];
    for (int i = lo + 1; i < hi; ++i) {
        int v = perm[i]; int j = i - 1;
        while (j >= lo && perm[j] > v) { perm[j + 1] = perm[j]; --j; }
        perm[j + 1] = v;
    }
}
__global__ void permute_sd(const int* __restrict__ perm, const int* __restrict__ src,
                           const int* __restrict__ dst, int* __restrict__ srcP,
                           int* __restrict__ dstP, int E) {
    int i = blockIdx.x * 256 + threadIdx.x;
    if (i < E) { int e = perm[i]; srcP[i] = src[e]; dstP[i] = dst[e]; }
}
__global__ void permute_all(const int* __restrict__ perm, const int* __restrict__ src,
                            const int* __restrict__ dst, const float* __restrict__ Ef,
                            int* __restrict__ srcP, int* __restrict__ dstP,
                            unsigned short* __restrict__ Ebf, int nE) {
    long long idx = (long long)blockIdx.x * 256 + threadIdx.x;
    if (idx >= (long long)nE * 16) return;
    int p = (int)(idx >> 4), q = (int)(idx & 15);
    int e = perm[p];
    if (q == 0) { srcP[p] = src[e]; dstP[p] = dst[e]; }
    float4 v = *(const float4*)&Ef[(size_t)e * 64 + q * 4];
    unsigned short* o = &Ebf[(size_t)p * 64 + q * 4];
    o[0] = f2bf_fast(v.x); o[1] = f2bf_fast(v.y);
    o[2] = f2bf_fast(v.z); o[3] = f2bf_fast(v.w);
}

// ---------------- node GEMM via split-bf16 MFMA (f32-accurate) ----------------
template<int ACT>
__global__ __launch_bounds__(256) void node_mfma3(
    const float* __restrict__ X, const unsigned short* __restrict__ WThi,
    const unsigned short* __restrict__ WTlo, const float* __restrict__ b,
    float* __restrict__ Y, int N)
{
    __shared__ unsigned short sHi[32 * PK2];
    __shared__ unsigned short sLo[32 * PK2];
    const int tid = threadIdx.x;
    const int r0 = blockIdx.x * 32;
    {
        const int r = tid >> 3, c0 = (tid & 7) * 16;
        const int row = min(r0 + r, N - 1);
        const float4* s4 = (const float4*)&X[(size_t)row * 128 + c0];
        unsigned short* dh = &sHi[r * PK2 + c0];
        unsigned short* dl = &sLo[r * PK2 + c0];
#pragma unroll
        for (int j = 0; j < 4; ++j) {
            float4 v = s4[j];
            float c[4] = { v.x, v.y, v.z, v.w };
#pragma unroll
            for (int q = 0; q < 4; ++q) {
                unsigned short h = f2bf_fast(c[q]);
                dh[j * 4 + q] = h;
                dl[j * 4 + q] = f2bf_fast(c[q] - bf2f(h));
            }
        }
    }
    __syncthreads();
    const int w = tid >> 6, l = tid & 63, cb = w * 32, lr = l & 15, hi4 = l >> 4, lk = hi4 * 8;
    const float bb[2] = { b[cb + lr], b[cb + 16 + lr] };
    f32x4 acc[2][2];
#pragma unroll
    for (int mt = 0; mt < 2; ++mt)
#pragma unroll
        for (int nt = 0; nt < 2; ++nt)
            acc[mt][nt] = (f32x4){bb[nt], bb[nt], bb[nt], bb[nt]};
    bf16x8 Bh[2][4], Bl[2][4];
#pragma unroll
    for (int nt = 0; nt < 2; ++nt)
#pragma unroll
        for (int kt = 0; kt < 4; ++kt) {
            Bh[nt][kt] = *(const bf16x8*)&WThi[(size_t)(cb + nt*16 + lr) * PK2 + kt*32 + lk];
            Bl[nt][kt] = *(const bf16x8*)&WTlo[(size_t)(cb + nt*16 + lr) * PK2 + kt*32 + lk];
        }
#pragma unroll
    for (int kt = 0; kt < 4; ++kt)
#pragma unroll
        for (int mt = 0; mt < 2; ++mt) {
            bf16x8 Ah = *(const bf16x8*)&sHi[(mt*16 + lr) * PK2 + kt*32 + lk];
            bf16x8 Al = *(const bf16x8*)&sLo[(mt*16 + lr) * PK2 + kt*32 + lk];
#pragma unroll
            for (int nt = 0; nt < 2; ++nt) {
                acc[mt][nt] = __builtin_amdgcn_mfma_f32_16x16x32_bf16(Ah, Bh[nt][kt], acc[mt][nt], 0, 0, 0);
                acc[mt][nt] = __builtin_amdgcn_mfma_f32_16x16x32_bf16(Al, Bh[nt][kt], acc[mt][nt], 0, 0, 0);
                acc[mt][nt] = __builtin_amdgcn_mfma_f32_16x16x32_bf16(Ah, Bl[nt][kt], acc[mt][nt], 0, 0, 0);
            }
        }
#pragma unroll
    for (int mt = 0; mt < 2; ++mt)
#pragma unroll
        for (int nt = 0; nt < 2; ++nt) {
            const int col = cb + nt*16 + lr;
#pragma unroll
            for (int r = 0; r < 4; ++r) {
                const int row = r0 + mt*16 + hi4*4 + r;
                if (row < N) {
                    float v = acc[mt][nt][r];
                    if (ACT) v = tanhf(sspf(v));
                    Y[(size_t)row * 128 + col] = v;
                }
            }
        }
}

// ---------------- fused middle: HVout = tanh(ssp(AGG@o1W+o1b)) @ n2W + n2b ----------------
__global__ __launch_bounds__(256) void node_mid(
    const float* __restrict__ AGG,
    const unsigned short* __restrict__ W1hi, const unsigned short* __restrict__ W1lo,
    const float* __restrict__ b1,
    const unsigned short* __restrict__ W2hi, const unsigned short* __restrict__ W2lo,
    const float* __restrict__ b2,
    float* __restrict__ HVout, int N)
{
    __shared__ unsigned short sHi[32 * PK2];
    __shared__ unsigned short sLo[32 * PK2];
    const int tid = threadIdx.x;
    const int r0 = blockIdx.x * 32;
    {
        const int r = tid >> 3, c0 = (tid & 7) * 16;
        const int row = min(r0 + r, N - 1);
        const float4* s4 = (const float4*)&AGG[(size_t)row * 128 + c0];
        unsigned short* dh = &sHi[r * PK2 + c0];
        unsigned short* dl = &sLo[r * PK2 + c0];
#pragma unroll
        for (int j = 0; j < 4; ++j) {
            float4 v = s4[j];
            float c[4] = { v.x, v.y, v.z, v.w };
#pragma unroll
            for (int q = 0; q < 4; ++q) {
                unsigned short h = f2bf_fast(c[q]);
                dh[j * 4 + q] = h;
                dl[j * 4 + q] = f2bf_fast(c[q] - bf2f(h));
            }
        }
    }
    __syncthreads();
    const int w = tid >> 6, l = tid & 63, cb = w * 32, lr = l & 15, hi4 = l >> 4, lk = hi4 * 8;

    f32x4 acc1[2][2];
    {
        const float bb[2] = { b1[cb + lr], b1[cb + 16 + lr] };
#pragma unroll
        for (int mt = 0; mt < 2; ++mt)
#pragma unroll
            for (int nt = 0; nt < 2; ++nt)
                acc1[mt][nt] = (f32x4){bb[nt], bb[nt], bb[nt], bb[nt]};
        bf16x8 Bh[2][4], Bl[2][4];
#pragma unroll
        for (int nt = 0; nt < 2; ++nt)
#pragma unroll
            for (int kt = 0; kt < 4; ++kt) {
                Bh[nt][kt] = *(const bf16x8*)&W1hi[(size_t)(cb + nt*16 + lr) * PK2 + kt*32 + lk];
                Bl[nt][kt] = *(const bf16x8*)&W1lo[(size_t)(cb + nt*16 + lr) * PK2 + kt*32 + lk];
            }
#pragma unroll
        for (int kt = 0; kt < 4; ++kt)
#pragma unroll
            for (int mt = 0; mt < 2; ++mt) {
                bf16x8 Ah = *(const bf16x8*)&sHi[(mt*16 + lr) * PK2 + kt*32 + lk];
                bf16x8 Al = *(const bf16x8*)&sLo[(mt*16 + lr) * PK2 + kt*32 + lk];
#pragma unroll
                for (int nt = 0; nt < 2; ++nt) {
                    acc1[mt][nt] = __builtin_amdgcn_mfma_f32_16x16x32_bf16(Ah, Bh[nt][kt], acc1[mt][nt], 0, 0, 0);
                    acc1[mt][nt] = __builtin_amdgcn_mfma_f32_16x16x32_bf16(Al, Bh[nt][kt], acc1[mt][nt], 0, 0, 0);
                    acc1[mt][nt] = __builtin_amdgcn_mfma_f32_16x16x32_bf16(Ah, Bl[nt][kt], acc1[mt][nt], 0, 0, 0);
                }
            }
    }
    __syncthreads();
#pragma unroll
    for (int mt = 0; mt < 2; ++mt)
#pragma unroll
        for (int nt = 0; nt < 2; ++nt) {
            const int col = cb + nt*16 + lr;
#pragma unroll
            for (int r = 0; r < 4; ++r) {
                const int row = mt*16 + hi4*4 + r;
                float v = tanhf(sspf(acc1[mt][nt][r]));
                unsigned short h = f2bf_fast(v);
                sHi[row * PK2 + col] = h;
                sLo[row * PK2 + col] = f2bf_fast(v - bf2f(h));
            }
        }
    __syncthreads();

    f32x4 acc2[2][2];
    {
        const float bb[2] = { b2[cb + lr], b2[cb + 16 + lr] };
#pragma unroll
        for (int mt = 0; mt < 2; ++mt)
#pragma unroll
            for (int nt = 0; nt < 2; ++nt)
                acc2[mt][nt] = (f32x4){bb[nt], bb[nt], bb[nt], bb[nt]};
        bf16x8 Bh[2][4], Bl[2][4];
#pragma unroll
        for (int nt = 0; nt < 2; ++nt)
#pragma unroll
            for (int kt = 0; kt < 4; ++kt) {
                Bh[nt][kt] = *(const bf16x8*)&W2hi[(size_t)(cb + nt*16 + lr) * PK2 + kt*32 + lk];
                Bl[nt][kt] = *(const bf16x8*)&W2lo[(size_t)(cb + nt*16 + lr) * PK2 + kt*32 + lk];
            }
#pragma unroll
        for (int kt = 0; kt < 4; ++kt)
#pragma unroll
            for (int mt = 0; mt < 2; ++mt) {
                bf16x8 Ah = *(const bf16x8*)&sHi[(mt*16 + lr) * PK2 + kt*32 + lk];
                bf16x8 Al = *(const bf16x8*)&sLo[(mt*16 + lr) * PK2 + kt*32 + lk];
#pragma unroll
                for (int nt = 0; nt < 2; ++nt) {
                    acc2[mt][nt] = __builtin_amdgcn_mfma_f32_16x16x32_bf16(Ah, Bh[nt][kt], acc2[mt][nt], 0, 0, 0);
                    acc2[mt][nt] = __builtin_amdgcn_mfma_f32_16x16x32_bf16(Al, Bh[nt][kt], acc2[mt][nt], 0, 0, 0);
                    acc2[mt][nt] = __builtin_amdgcn_mfma_f32_16x16x32_bf16(Ah, Bl[nt][kt], acc2[mt][nt], 0, 0, 0);
                }
            }
    }
#pragma unroll
    for (int mt = 0; mt < 2; ++mt)
#pragma unroll
        for (int nt = 0; nt < 2; ++nt) {
            const int col = cb + nt*16 + lr;
#pragma unroll
            for (int r = 0; r < 4; ++r) {
                const int row = r0 + mt*16 + hi4*4 + r;
                if (row < N) HVout[(size_t)row * 128 + col] = acc2[mt][nt][r];
            }
        }
}

// ---------------- persistent fused edge MLP + gather/filter (msg-store CSR path) ----------------
// EPI 0: store packed f16 msg pairs to MSG chunk. EPI 1: per-element f32 atomicAdd (fallback).
// Grid-stride over 64-edge tiles; weight fragments loop-invariant.
template<int MODE, int EPI>
__global__ __launch_bounds__(256) void edge_mfma(
    const unsigned short* __restrict__ Ebf, const float* __restrict__ Ef,
    const int* __restrict__ perm,
    const int* __restrict__ srcA, const int* __restrict__ dstA,
    const float* __restrict__ HV,
    const unsigned short* __restrict__ W1T, const float* __restrict__ b1,
    const unsigned short* __restrict__ W2T, const float* __restrict__ b2,
    float* __restrict__ OUTP, int c0, int c1)
{
    __shared__ unsigned short sT1[64 * PK2];
    __shared__ int sSrc[64], sDst[64];
    __shared__ unsigned short sE[(MODE == 1) ? 64 * PK1 : 4];

    const int tid = threadIdx.x;
    const int w = tid >> 6, l = tid & 63, cb = w * 32, lr = l & 15, hi4 = l >> 4, lk = hi4 * 8;
    const float bb1[2] = { b1[cb + lr], b1[cb + 16 + lr] };
    const float bb2[2] = { b2[cb + lr], b2[cb + 16 + lr] };

    // loop-invariant weight fragments
    bf16x8 B1[2][2];
#pragma unroll
    for (int nt = 0; nt < 2; ++nt)
#pragma unroll
        for (int kt = 0; kt < 2; ++kt)
            B1[nt][kt] = *(const bf16x8*)&W1T[(size_t)(cb + nt*16 + lr) * PK1 + kt*32 + lk];
    bf16x8 B2[2][4];
#pragma unroll
    for (int nt = 0; nt < 2; ++nt)
#pragma unroll
        for (int kt = 0; kt < 4; ++kt)
            B2[nt][kt] = *(const bf16x8*)&W2T[(size_t)(cb + nt*16 + lr) * PK2 + kt*32 + lk];

    const int nTiles = (c1 - c0 + 63) / 64;
    for (int t = blockIdx.x; t < nTiles; t += gridDim.x) {
        const int e0 = c0 + t * 64;

        if (tid < 64) {
            int gi = min(e0 + tid, c1 - 1);
            sSrc[tid] = srcA[gi];
            if (EPI == 1) sDst[tid] = dstA[gi];
        }
        if (MODE == 1) {
            const int r = tid >> 2, cc0 = (tid & 3) * 16;
            int gi = e0 + r;
            int e = (gi < c1) ? (perm ? perm[gi] : gi) : 0;
            const float4* s4 = (const float4*)&Ef[(size_t)e * 64 + cc0];
            unsigned short* dr = &sE[r * PK1 + cc0];
#pragma unroll
            for (int j = 0; j < 4; ++j) {
                float4 v = s4[j];
                dr[j*4+0] = f2bf_fast(v.x); dr[j*4+1] = f2bf_fast(v.y);
                dr[j*4+2] = f2bf_fast(v.z); dr[j*4+3] = f2bf_fast(v.w);
            }
        }
        __syncthreads();   // staging ready (also separates prev tile's sT1 reads)

        // GEMM1: T1 = ssp(E @ W1 + b1)
        f32x4 acc1[4][2];
#pragma unroll
        for (int mt = 0; mt < 4; ++mt)
#pragma unroll
            for (int nt = 0; nt < 2; ++nt)
                acc1[mt][nt] = (f32x4){bb1[nt], bb1[nt], bb1[nt], bb1[nt]};
#pragma unroll
        for (int kt = 0; kt < 2; ++kt)
#pragma unroll
            for (int mt = 0; mt < 4; ++mt) {
                bf16x8 A;
                if (MODE == 0) {
                    const int row = min(e0 + mt*16 + lr, c1 - 1);
                    A = *(const bf16x8*)&Ebf[(size_t)row * 64 + kt*32 + lk];
                } else {
                    A = *(const bf16x8*)&sE[(mt*16 + lr) * PK1 + kt*32 + lk];
                }
#pragma unroll
                for (int nt = 0; nt < 2; ++nt)
                    acc1[mt][nt] = __builtin_amdgcn_mfma_f32_16x16x32_bf16(A, B1[nt][kt], acc1[mt][nt], 0, 0, 0);
            }

#pragma unroll
        for (int mt = 0; mt < 4; ++mt)
#pragma unroll
            for (int nt = 0; nt < 2; ++nt) {
                const int col = cb + nt*16 + lr;
#pragma unroll
                for (int r = 0; r < 4; ++r) {
                    const int row = mt*16 + hi4*4 + r;
                    sT1[row * PK2 + col] = f2bf_fast(sspf(acc1[mt][nt][r]));
                }
            }
        __syncthreads();   // sT1 ready

        // GEMM2: he = ssp(T1 @ W2 + b2)
        f32x4 acc2[4][2];
#pragma unroll
        for (int mt = 0; mt < 4; ++mt)
#pragma unroll
            for (int nt = 0; nt < 2; ++nt)
                acc2[mt][nt] = (f32x4){bb2[nt], bb2[nt], bb2[nt], bb2[nt]};
#pragma unroll
        for (int kt = 0; kt < 4; ++kt)
#pragma unroll
            for (int mt = 0; mt < 4; ++mt) {
                bf16x8 A = *(const bf16x8*)&sT1[(mt*16 + lr) * PK2 + kt*32 + lk];
#pragma unroll
                for (int nt = 0; nt < 2; ++nt)
                    acc2[mt][nt] = __builtin_amdgcn_mfma_f32_16x16x32_bf16(A, B2[nt][kt], acc2[mt][nt], 0, 0, 0);
            }

        const int col0 = cb + lr, col1 = cb + 16 + lr;
#pragma unroll
        for (int mt = 0; mt < 4; ++mt) {
#pragma unroll
            for (int r = 0; r < 4; ++r) {
                const int row = mt*16 + hi4*4 + r;
                if (e0 + row < c1) {
                    const float he0 = sspf(acc2[mt][0][r]);
                    const float he1 = sspf(acc2[mt][1][r]);
                    const int s = sSrc[row];
                    const float m0 = HV[(size_t)s * 128 + col0] * he0;
                    const float m1 = HV[(size_t)s * 128 + col1] * he1;
                    if (EPI == 0) {
                        h16x2 p; p.x = (_Float16)m0; p.y = (_Float16)m1;
                        ((unsigned*)OUTP)[(size_t)(e0 + row - c0) * 64 + (cb >> 1) + lr] =
                            __builtin_bit_cast(unsigned, p);
                    } else {
                        const int d = sDst[row];
                        atomicAdd(&OUTP[(size_t)d * 128 + col0], m0);
                        atomicAdd(&OUTP[(size_t)d * 128 + col1], m1);
                    }
                }
            }
        }
        __syncthreads();   // epilogue's sSrc/sT1 lifetime ends before next tile staging
    }
}

// ---------------- deterministic CSR segmented sum over packed f16 msgs ----------------
template<int ACCUM>
__global__ __launch_bounds__(256) void gather_kernel(
    const unsigned* __restrict__ MSG, const int* __restrict__ row_ptr,
    const int* __restrict__ hist, float* __restrict__ AGG, int N, int c0, int c1)
{
    const int node = blockIdx.x * 8 + (threadIdx.x >> 5);
    if (node >= N) return;
    const int lane = threadIdx.x & 31;
    const int s0 = 2 * lane, s1 = 2 * lane + 1;
    const int lo = row_ptr[node];
    const int jlo = max(lo, c0), jhi = min(lo + hist[node], c1);
    if (ACCUM && jlo >= jhi) return;
    float a0 = 0.f, a1 = 0.f, b0 = 0.f, b1 = 0.f;
    for (int j = jlo; j < jhi; ++j) {
        const uint2 v = *(const uint2*)&MSG[(size_t)(j - c0) * 64 + s0];
        const h16x2 pa = __builtin_bit_cast(h16x2, v.x);
        const h16x2 pb = __builtin_bit_cast(h16x2, v.y);
        a0 += (float)pa.x; a1 += (float)pa.y;
        b0 += (float)pb.x; b1 += (float)pb.y;
    }
    const int cA = (s0 >> 4) * 32 + (s0 & 15);
    const int cB = (s1 >> 4) * 32 + (s1 & 15);
    float* base = &AGG[(size_t)node * 128];
    if (ACCUM) {
        base[cA] += a0; base[cA + 16] += a1;
        base[cB] += b0; base[cB + 16] += b1;
    } else {
        base[cA] = a0; base[cA + 16] = a1;
        base[cB] = b0; base[cB + 16] = b1;
    }
}

extern "C" void kernel_launch(void* const* d_in, const int* in_sizes, int n_in,
                              void* d_out, int out_size, void* d_ws, size_t ws_size,
                              hipStream_t stream) {
    const float* x    = (const float*)d_in[0];
    const float* e    = (const float*)d_in[1];
    const int*   src  = (const int*)  d_in[2];
    const int*   dst  = (const int*)  d_in[3];
    const float* n1W  = (const float*)d_in[4];
    const float* n1b  = (const float*)d_in[5];
    const float* e1W1 = (const float*)d_in[6];
    const float* e1b1 = (const float*)d_in[7];
    const float* e1W2 = (const float*)d_in[8];
    const float* e1b2 = (const float*)d_in[9];
    const float* o1W  = (const float*)d_in[10];
    const float* o1b  = (const float*)d_in[11];
    const float* n2W  = (const float*)d_in[12];
    const float* n2b  = (const float*)d_in[13];
    const float* e2W1 = (const float*)d_in[14];
    const float* e2b1 = (const float*)d_in[15];
    const float* e2W2 = (const float*)d_in[16];
    const float* e2b2 = (const float*)d_in[17];
    const float* o2W  = (const float*)d_in[18];
    const float* o2b  = (const float*)d_in[19];

    const int N = in_sizes[0] / 128;
    const int E = in_sizes[2];
    float* out = (float*)d_out;

    char* ws = (char*)d_ws;
    size_t off = 0;
    auto alloc = [&](size_t bytes) -> char* {
        char* p = ws + off;
        off = (off + bytes + 255) & ~(size_t)255;
        return p;
    };
    float* agg = (float*)alloc((size_t)N * 128 * 4);
    float* hv  = (float*)alloc((size_t)N * 128 * 4);
    unsigned short* w_e1w1 = (unsigned short*)alloc(128 * PK1 * 2);
    unsigned short* w_e1w2 = (unsigned short*)alloc(128 * PK2 * 2);
    unsigned short* w_e2w1 = (unsigned short*)alloc(128 * PK1 * 2);
    unsigned short* w_e2w2 = (unsigned short*)alloc(128 * PK2 * 2);
    unsigned short* n1hi = (unsigned short*)alloc(128 * PK2 * 2);
    unsigned short* n1lo = (unsigned short*)alloc(128 * PK2 * 2);
    unsigned short* o1hi = (unsigned short*)alloc(128 * PK2 * 2);
    unsigned short* o1lo = (unsigned short*)alloc(128 * PK2 * 2);
    unsigned short* n2hi = (unsigned short*)alloc(128 * PK2 * 2);
    unsigned short* n2lo = (unsigned short*)alloc(128 * PK2 * 2);
    unsigned short* o2hi = (unsigned short*)alloc(128 * PK2 * 2);
    unsigned short* o2lo = (unsigned short*)alloc(128 * PK2 * 2);
    int* perm    = (int*)alloc((size_t)E * 4);
    int* srcP    = (int*)alloc((size_t)E * 4);
    int* dstP    = (int*)alloc((size_t)E * 4);
    int* hist    = (int*)alloc((size_t)N * 4);
    int* cursor  = (int*)alloc((size_t)N * 4);
    int* row_ptr = (int*)alloc((size_t)N * 4);
    const size_t sort_need = off;
    unsigned short* Ebf = (unsigned short*)alloc((size_t)E * 64 * 2);
    const bool useEbf  = (ws_size >= off);
    const bool useSort = (ws_size >= sort_need);

    // message-chunk budget, 256 B per packed msg row
    size_t chunkE = 0;
    int nChunks = 0;
    unsigned* msg = nullptr;
    if (useSort && useEbf) {
        size_t budget = (ws_size > off) ? (ws_size - off) : 0;
        size_t rows = (budget / 256) & ~(size_t)63;
        if (rows > (size_t)E) rows = ((size_t)E + 63) & ~(size_t)63;
        if (rows >= 4096) {
            chunkE = rows;
            nChunks = (int)((E + chunkE - 1) / chunkE);
            if (nChunks <= 40) msg = (unsigned*)alloc(chunkE * 256);
            else { chunkE = 0; nChunks = 0; }
        }
    }
    const bool useStore = (msg != nullptr);

    convert_all<<<544, 256, 0, stream>>>(
        e1W1, e1W2, e2W1, e2W2, n1W, o1W, n2W, o2W,
        w_e1w1, w_e1w2, w_e2w1, w_e2w2,
        n1hi, n1lo, o1hi, o1lo, n2hi, n2lo, o2hi, o2lo);

    const int* sA = src;
    const int* dA = dst;
    const int* permArg = nullptr;
    if (useSort) {
        hipMemsetAsync(hist, 0, (size_t)N * 4, stream);
        hist_kernel<<<(E + 255)/256, 256, 0, stream>>>(dst, hist, E);
        scan_kernel<<<1, 1024, 0, stream>>>(hist, row_ptr, cursor, N);
        scatter_kernel<<<(E + 255)/256, 256, 0, stream>>>(dst, cursor, perm, E);
        sort_buckets<<<(N + 255)/256, 256, 0, stream>>>(row_ptr, hist, perm, N);
        if (useEbf) {
            permute_all<<<(int)(((size_t)E * 16 + 255)/256), 256, 0, stream>>>(
                perm, src, dst, e, srcP, dstP, Ebf, E);
        } else {
            permute_sd<<<(E + 255)/256, 256, 0, stream>>>(perm, src, dst, srcP, dstP, E);
        }
        sA = srcP; dA = dstP; permArg = perm;
    }

    const int nodeBlocks = (N + 31) / 32;
    const int gatherBlocks = (N + 7) / 8;
    const size_t nbytes = (size_t)N * 128 * 4;

    auto run_edge_layer = [&](const unsigned short* W1T, const float* b1,
                              const unsigned short* W2T, const float* b2) {
        if (useStore) {
            if (nChunks == 1) {
                const int tiles = (E + 63) / 64;
                const int blocks = min(tiles, 2048);
                edge_mfma<0, 0><<<blocks, 256, 0, stream>>>(
                    Ebf, nullptr, nullptr, sA, dA, hv, W1T, b1, W2T, b2, (float*)msg, 0, E);
                gather_kernel<0><<<gatherBlocks, 256, 0, stream>>>(
                    msg, row_ptr, hist, agg, N, 0, E);
            } else {
                hipMemsetAsync(agg, 0, nbytes, stream);
                for (int k = 0; k < nChunks; ++k) {
                    const int c0 = (int)(k * chunkE);
                    const int c1 = (int)min((size_t)E, c0 + chunkE);
                    const int tiles = (c1 - c0 + 63) / 64;
                    const int blocks = min(tiles, 2048);
                    edge_mfma<0, 0><<<blocks, 256, 0, stream>>>(
                        Ebf, nullptr, nullptr, sA, dA, hv, W1T, b1, W2T, b2, (float*)msg, c0, c1);
                    gather_kernel<1><<<gatherBlocks, 256, 0, stream>>>(
                        msg, row_ptr, hist, agg, N, c0, c1);
                }
            }
        } else if (useEbf) {
            hipMemsetAsync(agg, 0, nbytes, stream);
            edge_mfma<0, 1><<<min((E + 63)/64, 2048), 256, 0, stream>>>(
                Ebf, nullptr, nullptr, sA, dA, hv, W1T, b1, W2T, b2, agg, 0, E);
        } else {
            hipMemsetAsync(agg, 0, nbytes, stream);
            edge_mfma<1, 1><<<min((E + 63)/64, 2048), 256, 0, stream>>>(
                nullptr, e, permArg, sA, dA, hv, W1T, b1, W2T, b2, agg, 0, E);
        }
    };

    // ---- layer 1 ----
    node_mfma3<0><<<nodeBlocks, 256, 0, stream>>>(x, n1hi, n1lo, n1b, hv, N);
    run_edge_layer(w_e1w1, e1b1, w_e1w2, e1b2);

    // ---- fused middle ----
    node_mid<<<nodeBlocks, 256, 0, stream>>>(agg, o1hi, o1lo, o1b, n2hi, n2lo, n2b, hv, N);

    // ---- layer 2 ----
    run_edge_layer(w_e2w1, e2b1, w_e2w2, e2b2);
    node_mfma3<1><<<nodeBlocks, 256, 0, stream>>>(agg, o2hi, o2lo, o2b, out, N);
}

// Round 18
// 664.301 us; speedup vs baseline: 1.1036x; 1.1036x over previous
//
#include <hip/hip_runtime.h>
#include <hip/hip_bf16.h>
#include <math.h>

typedef __bf16 bf16x8 __attribute__((ext_vector_type(8)));
typedef float f32x4 __attribute__((ext_vector_type(4)));
typedef _Float16 h16x2 __attribute__((ext_vector_type(2)));

#define LOG2F 0.6931471805599453f
#define PK1 72     // padded row length (bf16) for K=64 tiles
#define PK2 136    // padded row length (bf16) for K=128 tiles

__device__ __forceinline__ float sspf(float x) {
    float t = __expf(-fabsf(x));
    return fmaxf(x, 0.0f) + __logf(1.0f + t) - LOG2F;
}
__device__ __forceinline__ unsigned short f2bf(float f) {
    union { float f; unsigned u; } v; v.f = f;
    unsigned r = v.u + 0x7FFF + ((v.u >> 16) & 1);
    return (unsigned short)(r >> 16);
}
__device__ __forceinline__ float bf2f(unsigned short u) {
    union { unsigned u; float f; } v; v.u = ((unsigned)u) << 16;
    return v.f;
}
__device__ __forceinline__ unsigned short f2bf_fast(float f) {
    __bf16 h = (__bf16)f;
    return __builtin_bit_cast(unsigned short, h);
}

// ---------------- all weight pre-converts in one kernel ----------------
__global__ void convert_all(
    const float* __restrict__ A0, const float* __restrict__ A1,
    const float* __restrict__ A2, const float* __restrict__ A3,
    const float* __restrict__ A4, const float* __restrict__ A5,
    const float* __restrict__ A6, const float* __restrict__ A7,
    unsigned short* __restrict__ O0, unsigned short* __restrict__ O1,
    unsigned short* __restrict__ O2, unsigned short* __restrict__ O3,
    unsigned short* __restrict__ H4, unsigned short* __restrict__ L4,
    unsigned short* __restrict__ H5, unsigned short* __restrict__ L5,
    unsigned short* __restrict__ H6, unsigned short* __restrict__ L6,
    unsigned short* __restrict__ H7, unsigned short* __restrict__ L7)
{
    const int seg = blockIdx.x / 68;
    const int idx = (blockIdx.x % 68) * 256 + threadIdx.x;
    if (seg < 4) {
        const int PK = (seg == 0 || seg == 2) ? PK1 : PK2;
        const int K  = (seg == 0 || seg == 2) ? 64 : 128;
        if (idx >= 128 * PK) return;
        const float* W = (seg == 0) ? A0 : (seg == 1) ? A1 : (seg == 2) ? A2 : A3;
        unsigned short* O = (seg == 0) ? O0 : (seg == 1) ? O1 : (seg == 2) ? O2 : O3;
        int n = idx / PK, k = idx - n * PK;
        O[idx] = (k < K) ? f2bf(W[k * 128 + n]) : (unsigned short)0;
    } else {
        if (idx >= 128 * PK2) return;
        const float* W = (seg == 4) ? A4 : (seg == 5) ? A5 : (seg == 6) ? A6 : A7;
        unsigned short* H = (seg == 4) ? H4 : (seg == 5) ? H5 : (seg == 6) ? H6 : H7;
        unsigned short* L = (seg == 4) ? L4 : (seg == 5) ? L5 : (seg == 6) ? L6 : L7;
        int n = idx / PK2, k = idx - n * PK2;
        unsigned short h = 0, lo = 0;
        if (k < 128) {
            float w = W[k * 128 + n];
            h = f2bf(w);
            lo = f2bf(w - bf2f(h));
        }
        H[idx] = h; L[idx] = lo;
    }
}

// ---------------- deterministic counting sort by dst ----------------
__global__ void hist_kernel(const int* __restrict__ dst, int* __restrict__ hist, int E) {
    int i = blockIdx.x * 256 + threadIdx.x;
    if (i < E) atomicAdd(&hist[dst[i]], 1);
}
__global__ void scan_kernel(const int* __restrict__ hist, int* __restrict__ row_ptr,
                            int* __restrict__ cursor, int N) {
    __shared__ int part[1024];
    const int tid = threadIdx.x;
    const int chunk = (N + 1023) / 1024;
    const int lo = min(tid * chunk, N);
    const int hi = min(lo + chunk, N);
    int s = 0;
    for (int i = lo; i < hi; ++i) s += hist[i];
    part[tid] = s;
    __syncthreads();
    // Hillis-Steele inclusive scan over 1024 partials
    for (int d = 1; d < 1024; d <<= 1) {
        int t = (tid >= d) ? part[tid - d] : 0;
        __syncthreads();
        part[tid] += t;
        __syncthreads();
    }
    int run = part[tid] - s;   // exclusive prefix for this thread's chunk
    for (int i = lo; i < hi; ++i) { row_ptr[i] = run; cursor[i] = run; run += hist[i]; }
}
__global__ void scatter_kernel(const int* __restrict__ dst, int* __restrict__ cursor,
                               int* __restrict__ perm, int E) {
    int i = blockIdx.x * 256 + threadIdx.x;
    if (i < E) { int p = atomicAdd(&cursor[dst[i]], 1); perm[p] = i; }
}
__global__ void sort_buckets(const int* __restrict__ row_ptr, const int* __restrict__ hist,
                             int* __restrict__ perm, int N) {
    int n = blockIdx.x * 256 + threadIdx.x;
    if (n >= N) return;
    const int lo = row_ptr[n], hi = lo + hist[n];
    for (int i = lo + 1; i < hi; ++i) {
        int v = perm[i]; int j = i - 1;
        while (j >= lo && perm[j] > v) { perm[j + 1] = perm[j]; --j; }
        perm[j + 1] = v;
    }
}
__global__ void permute_sd(const int* __restrict__ perm, const int* __restrict__ src,
                           const int* __restrict__ dst, int* __restrict__ srcP,
                           int* __restrict__ dstP, int E) {
    int i = blockIdx.x * 256 + threadIdx.x;
    if (i < E) { int e = perm[i]; srcP[i] = src[e]; dstP[i] = dst[e]; }
}
__global__ void permute_all(const int* __restrict__ perm, const int* __restrict__ src,
                            const int* __restrict__ dst, const float* __restrict__ Ef,
                            int* __restrict__ srcP, int* __restrict__ dstP,
                            unsigned short* __restrict__ Ebf, int nE) {
    long long idx = (long long)blockIdx.x * 256 + threadIdx.x;
    if (idx >= (long long)nE * 16) return;
    int p = (int)(idx >> 4), q = (int)(idx & 15);
    int e = perm[p];
    if (q == 0) { srcP[p] = src[e]; dstP[p] = dst[e]; }
    float4 v = *(const float4*)&Ef[(size_t)e * 64 + q * 4];
    unsigned short* o = &Ebf[(size_t)p * 64 + q * 4];
    o[0] = f2bf_fast(v.x); o[1] = f2bf_fast(v.y);
    o[2] = f2bf_fast(v.z); o[3] = f2bf_fast(v.w);
}

// ---------------- node GEMM via split-bf16 MFMA (f32-accurate) ----------------
template<int ACT>
__global__ __launch_bounds__(256) void node_mfma3(
    const float* __restrict__ X, const unsigned short* __restrict__ WThi,
    const unsigned short* __restrict__ WTlo, const float* __restrict__ b,
    float* __restrict__ Y, int N)
{
    __shared__ unsigned short sHi[32 * PK2];
    __shared__ unsigned short sLo[32 * PK2];
    const int tid = threadIdx.x;
    const int r0 = blockIdx.x * 32;
    {
        const int r = tid >> 3, c0 = (tid & 7) * 16;
        const int row = min(r0 + r, N - 1);
        const float4* s4 = (const float4*)&X[(size_t)row * 128 + c0];
        unsigned short* dh = &sHi[r * PK2 + c0];
        unsigned short* dl = &sLo[r * PK2 + c0];
#pragma unroll
        for (int j = 0; j < 4; ++j) {
            float4 v = s4[j];
            float c[4] = { v.x, v.y, v.z, v.w };
#pragma unroll
            for (int q = 0; q < 4; ++q) {
                unsigned short h = f2bf_fast(c[q]);
                dh[j * 4 + q] = h;
                dl[j * 4 + q] = f2bf_fast(c[q] - bf2f(h));
            }
        }
    }
    __syncthreads();
    const int w = tid >> 6, l = tid & 63, cb = w * 32, lr = l & 15, hi4 = l >> 4, lk = hi4 * 8;
    const float bb[2] = { b[cb + lr], b[cb + 16 + lr] };
    f32x4 acc[2][2];
#pragma unroll
    for (int mt = 0; mt < 2; ++mt)
#pragma unroll
        for (int nt = 0; nt < 2; ++nt)
            acc[mt][nt] = (f32x4){bb[nt], bb[nt], bb[nt], bb[nt]};
    bf16x8 Bh[2][4], Bl[2][4];
#pragma unroll
    for (int nt = 0; nt < 2; ++nt)
#pragma unroll
        for (int kt = 0; kt < 4; ++kt) {
            Bh[nt][kt] = *(const bf16x8*)&WThi[(size_t)(cb + nt*16 + lr) * PK2 + kt*32 + lk];
            Bl[nt][kt] = *(const bf16x8*)&WTlo[(size_t)(cb + nt*16 + lr) * PK2 + kt*32 + lk];
        }
#pragma unroll
    for (int kt = 0; kt < 4; ++kt)
#pragma unroll
        for (int mt = 0; mt < 2; ++mt) {
            bf16x8 Ah = *(const bf16x8*)&sHi[(mt*16 + lr) * PK2 + kt*32 + lk];
            bf16x8 Al = *(const bf16x8*)&sLo[(mt*16 + lr) * PK2 + kt*32 + lk];
#pragma unroll
            for (int nt = 0; nt < 2; ++nt) {
                acc[mt][nt] = __builtin_amdgcn_mfma_f32_16x16x32_bf16(Ah, Bh[nt][kt], acc[mt][nt], 0, 0, 0);
                acc[mt][nt] = __builtin_amdgcn_mfma_f32_16x16x32_bf16(Al, Bh[nt][kt], acc[mt][nt], 0, 0, 0);
                acc[mt][nt] = __builtin_amdgcn_mfma_f32_16x16x32_bf16(Ah, Bl[nt][kt], acc[mt][nt], 0, 0, 0);
            }
        }
#pragma unroll
    for (int mt = 0; mt < 2; ++mt)
#pragma unroll
        for (int nt = 0; nt < 2; ++nt) {
            const int col = cb + nt*16 + lr;
#pragma unroll
            for (int r = 0; r < 4; ++r) {
                const int row = r0 + mt*16 + hi4*4 + r;
                if (row < N) {
                    float v = acc[mt][nt][r];
                    if (ACT) v = tanhf(sspf(v));
                    Y[(size_t)row * 128 + col] = v;
                }
            }
        }
}

// ---------------- fused middle: HVout = tanh(ssp(AGG@o1W+o1b)) @ n2W + n2b ----------------
__global__ __launch_bounds__(256) void node_mid(
    const float* __restrict__ AGG,
    const unsigned short* __restrict__ W1hi, const unsigned short* __restrict__ W1lo,
    const float* __restrict__ b1,
    const unsigned short* __restrict__ W2hi, const unsigned short* __restrict__ W2lo,
    const float* __restrict__ b2,
    float* __restrict__ HVout, int N)
{
    __shared__ unsigned short sHi[32 * PK2];
    __shared__ unsigned short sLo[32 * PK2];
    const int tid = threadIdx.x;
    const int r0 = blockIdx.x * 32;
    {
        const int r = tid >> 3, c0 = (tid & 7) * 16;
        const int row = min(r0 + r, N - 1);
        const float4* s4 = (const float4*)&AGG[(size_t)row * 128 + c0];
        unsigned short* dh = &sHi[r * PK2 + c0];
        unsigned short* dl = &sLo[r * PK2 + c0];
#pragma unroll
        for (int j = 0; j < 4; ++j) {
            float4 v = s4[j];
            float c[4] = { v.x, v.y, v.z, v.w };
#pragma unroll
            for (int q = 0; q < 4; ++q) {
                unsigned short h = f2bf_fast(c[q]);
                dh[j * 4 + q] = h;
                dl[j * 4 + q] = f2bf_fast(c[q] - bf2f(h));
            }
        }
    }
    __syncthreads();
    const int w = tid >> 6, l = tid & 63, cb = w * 32, lr = l & 15, hi4 = l >> 4, lk = hi4 * 8;

    f32x4 acc1[2][2];
    {
        const float bb[2] = { b1[cb + lr], b1[cb + 16 + lr] };
#pragma unroll
        for (int mt = 0; mt < 2; ++mt)
#pragma unroll
            for (int nt = 0; nt < 2; ++nt)
                acc1[mt][nt] = (f32x4){bb[nt], bb[nt], bb[nt], bb[nt]};
        bf16x8 Bh[2][4], Bl[2][4];
#pragma unroll
        for (int nt = 0; nt < 2; ++nt)
#pragma unroll
            for (int kt = 0; kt < 4; ++kt) {
                Bh[nt][kt] = *(const bf16x8*)&W1hi[(size_t)(cb + nt*16 + lr) * PK2 + kt*32 + lk];
                Bl[nt][kt] = *(const bf16x8*)&W1lo[(size_t)(cb + nt*16 + lr) * PK2 + kt*32 + lk];
            }
#pragma unroll
        for (int kt = 0; kt < 4; ++kt)
#pragma unroll
            for (int mt = 0; mt < 2; ++mt) {
                bf16x8 Ah = *(const bf16x8*)&sHi[(mt*16 + lr) * PK2 + kt*32 + lk];
                bf16x8 Al = *(const bf16x8*)&sLo[(mt*16 + lr) * PK2 + kt*32 + lk];
#pragma unroll
                for (int nt = 0; nt < 2; ++nt) {
                    acc1[mt][nt] = __builtin_amdgcn_mfma_f32_16x16x32_bf16(Ah, Bh[nt][kt], acc1[mt][nt], 0, 0, 0);
                    acc1[mt][nt] = __builtin_amdgcn_mfma_f32_16x16x32_bf16(Al, Bh[nt][kt], acc1[mt][nt], 0, 0, 0);
                    acc1[mt][nt] = __builtin_amdgcn_mfma_f32_16x16x32_bf16(Ah, Bl[nt][kt], acc1[mt][nt], 0, 0, 0);
                }
            }
    }
    __syncthreads();
#pragma unroll
    for (int mt = 0; mt < 2; ++mt)
#pragma unroll
        for (int nt = 0; nt < 2; ++nt) {
            const int col = cb + nt*16 + lr;
#pragma unroll
            for (int r = 0; r < 4; ++r) {
                const int row = mt*16 + hi4*4 + r;
                float v = tanhf(sspf(acc1[mt][nt][r]));
                unsigned short h = f2bf_fast(v);
                sHi[row * PK2 + col] = h;
                sLo[row * PK2 + col] = f2bf_fast(v - bf2f(h));
            }
        }
    __syncthreads();

    f32x4 acc2[2][2];
    {
        const float bb[2] = { b2[cb + lr], b2[cb + 16 + lr] };
#pragma unroll
        for (int mt = 0; mt < 2; ++mt)
#pragma unroll
            for (int nt = 0; nt < 2; ++nt)
                acc2[mt][nt] = (f32x4){bb[nt], bb[nt], bb[nt], bb[nt]};
        bf16x8 Bh[2][4], Bl[2][4];
#pragma unroll
        for (int nt = 0; nt < 2; ++nt)
#pragma unroll
            for (int kt = 0; kt < 4; ++kt) {
                Bh[nt][kt] = *(const bf16x8*)&W2hi[(size_t)(cb + nt*16 + lr) * PK2 + kt*32 + lk];
                Bl[nt][kt] = *(const bf16x8*)&W2lo[(size_t)(cb + nt*16 + lr) * PK2 + kt*32 + lk];
            }
#pragma unroll
        for (int kt = 0; kt < 4; ++kt)
#pragma unroll
            for (int mt = 0; mt < 2; ++mt) {
                bf16x8 Ah = *(const bf16x8*)&sHi[(mt*16 + lr) * PK2 + kt*32 + lk];
                bf16x8 Al = *(const bf16x8*)&sLo[(mt*16 + lr) * PK2 + kt*32 + lk];
#pragma unroll
                for (int nt = 0; nt < 2; ++nt) {
                    acc2[mt][nt] = __builtin_amdgcn_mfma_f32_16x16x32_bf16(Ah, Bh[nt][kt], acc2[mt][nt], 0, 0, 0);
                    acc2[mt][nt] = __builtin_amdgcn_mfma_f32_16x16x32_bf16(Al, Bh[nt][kt], acc2[mt][nt], 0, 0, 0);
                    acc2[mt][nt] = __builtin_amdgcn_mfma_f32_16x16x32_bf16(Ah, Bl[nt][kt], acc2[mt][nt], 0, 0, 0);
                }
            }
    }
#pragma unroll
    for (int mt = 0; mt < 2; ++mt)
#pragma unroll
        for (int nt = 0; nt < 2; ++nt) {
            const int col = cb + nt*16 + lr;
#pragma unroll
            for (int r = 0; r < 4; ++r) {
                const int row = r0 + mt*16 + hi4*4 + r;
                if (row < N) HVout[(size_t)row * 128 + col] = acc2[mt][nt][r];
            }
        }
}

// ---------------- fused edge MLP + gather/filter ----------------
// EPI 0: store packed f16 msg pairs to MSG chunk (deterministic CSR path).
//        slot layout: row*64 + w*16 + lr holds half2{m(col), m(col+16)}, col = w*32+lr.
// EPI 1: per-element f32 atomicAdd into AGG (stable fallback).
template<int MODE, int EPI>
__global__ __launch_bounds__(256) void edge_mfma(
    const unsigned short* __restrict__ Ebf, const float* __restrict__ Ef,
    const int* __restrict__ perm,
    const int* __restrict__ srcA, const int* __restrict__ dstA,
    const float* __restrict__ HV,
    const unsigned short* __restrict__ W1T, const float* __restrict__ b1,
    const unsigned short* __restrict__ W2T, const float* __restrict__ b2,
    float* __restrict__ OUTP, int c0, int c1)
{
    __shared__ unsigned short sT1[64 * PK2];
    __shared__ int sSrc[64], sDst[64];
    __shared__ unsigned short sE[(MODE == 1) ? 64 * PK1 : 4];

    const int tid = threadIdx.x;
    const int e0 = c0 + blockIdx.x * 64;

    if (tid < 64) {
        int gi = min(e0 + tid, c1 - 1);
        sSrc[tid] = srcA[gi];
        if (EPI == 1) sDst[tid] = dstA[gi];
    }
    if (MODE == 1) {
        const int r = tid >> 2, cc0 = (tid & 3) * 16;
        int gi = e0 + r;
        int e = (gi < c1) ? (perm ? perm[gi] : gi) : 0;
        const float4* s4 = (const float4*)&Ef[(size_t)e * 64 + cc0];
        unsigned short* dr = &sE[r * PK1 + cc0];
#pragma unroll
        for (int j = 0; j < 4; ++j) {
            float4 v = s4[j];
            dr[j*4+0] = f2bf_fast(v.x); dr[j*4+1] = f2bf_fast(v.y);
            dr[j*4+2] = f2bf_fast(v.z); dr[j*4+3] = f2bf_fast(v.w);
        }
    }
    __syncthreads();

    const int w = tid >> 6, l = tid & 63, cb = w * 32, lr = l & 15, hi4 = l >> 4, lk = hi4 * 8;
    const float bb1[2] = { b1[cb + lr], b1[cb + 16 + lr] };
    const float bb2[2] = { b2[cb + lr], b2[cb + 16 + lr] };

    bf16x8 B1[2][2];
#pragma unroll
    for (int nt = 0; nt < 2; ++nt)
#pragma unroll
        for (int kt = 0; kt < 2; ++kt)
            B1[nt][kt] = *(const bf16x8*)&W1T[(size_t)(cb + nt*16 + lr) * PK1 + kt*32 + lk];

    f32x4 acc1[4][2];
#pragma unroll
    for (int mt = 0; mt < 4; ++mt)
#pragma unroll
        for (int nt = 0; nt < 2; ++nt)
            acc1[mt][nt] = (f32x4){bb1[nt], bb1[nt], bb1[nt], bb1[nt]};
#pragma unroll
    for (int kt = 0; kt < 2; ++kt)
#pragma unroll
        for (int mt = 0; mt < 4; ++mt) {
            bf16x8 A;
            if (MODE == 0) {
                const int row = min(e0 + mt*16 + lr, c1 - 1);
                A = *(const bf16x8*)&Ebf[(size_t)row * 64 + kt*32 + lk];
            } else {
                A = *(const bf16x8*)&sE[(mt*16 + lr) * PK1 + kt*32 + lk];
            }
#pragma unroll
            for (int nt = 0; nt < 2; ++nt)
                acc1[mt][nt] = __builtin_amdgcn_mfma_f32_16x16x32_bf16(A, B1[nt][kt], acc1[mt][nt], 0, 0, 0);
        }

#pragma unroll
    for (int mt = 0; mt < 4; ++mt)
#pragma unroll
        for (int nt = 0; nt < 2; ++nt) {
            const int col = cb + nt*16 + lr;
#pragma unroll
            for (int r = 0; r < 4; ++r) {
                const int row = mt*16 + hi4*4 + r;
                sT1[row * PK2 + col] = f2bf_fast(sspf(acc1[mt][nt][r]));
            }
        }
    __syncthreads();

    bf16x8 B2[2][4];
#pragma unroll
    for (int nt = 0; nt < 2; ++nt)
#pragma unroll
        for (int kt = 0; kt < 4; ++kt)
            B2[nt][kt] = *(const bf16x8*)&W2T[(size_t)(cb + nt*16 + lr) * PK2 + kt*32 + lk];

    f32x4 acc2[4][2];
#pragma unroll
    for (int mt = 0; mt < 4; ++mt)
#pragma unroll
        for (int nt = 0; nt < 2; ++nt)
            acc2[mt][nt] = (f32x4){bb2[nt], bb2[nt], bb2[nt], bb2[nt]};
#pragma unroll
    for (int kt = 0; kt < 4; ++kt)
#pragma unroll
        for (int mt = 0; mt < 4; ++mt) {
            bf16x8 A = *(const bf16x8*)&sT1[(mt*16 + lr) * PK2 + kt*32 + lk];
#pragma unroll
            for (int nt = 0; nt < 2; ++nt)
                acc2[mt][nt] = __builtin_amdgcn_mfma_f32_16x16x32_bf16(A, B2[nt][kt], acc2[mt][nt], 0, 0, 0);
        }

    const int col0 = cb + lr, col1 = cb + 16 + lr;
#pragma unroll
    for (int mt = 0; mt < 4; ++mt) {
#pragma unroll
        for (int r = 0; r < 4; ++r) {
            const int row = mt*16 + hi4*4 + r;
            if (e0 + row < c1) {
                const float he0 = sspf(acc2[mt][0][r]);
                const float he1 = sspf(acc2[mt][1][r]);
                const int s = sSrc[row];
                const float m0 = HV[(size_t)s * 128 + col0] * he0;
                const float m1 = HV[(size_t)s * 128 + col1] * he1;
                if (EPI == 0) {
                    h16x2 p; p.x = (_Float16)m0; p.y = (_Float16)m1;
                    ((unsigned*)OUTP)[(size_t)(e0 + row - c0) * 64 + (cb >> 1) + lr] =
                        __builtin_bit_cast(unsigned, p);
                } else {
                    const int d = sDst[row];
                    atomicAdd(&OUTP[(size_t)d * 128 + col0], m0);
                    atomicAdd(&OUTP[(size_t)d * 128 + col1], m1);
                }
            }
        }
    }
}

// ---------------- deterministic CSR segmented sum over packed f16 msgs ----------------
// MSG row: 64 x half2; slot s -> cols (s>>4)*32 + (s&15) and +16.
// ACCUM=0: write agg (covers all nodes incl. empty). ACCUM=1: agg += (chunked).
template<int ACCUM>
__global__ __launch_bounds__(256) void gather_kernel(
    const unsigned* __restrict__ MSG, const int* __restrict__ row_ptr,
    const int* __restrict__ hist, float* __restrict__ AGG, int N, int c0, int c1)
{
    const int node = blockIdx.x * 8 + (threadIdx.x >> 5);
    if (node >= N) return;
    const int lane = threadIdx.x & 31;
    const int s0 = 2 * lane, s1 = 2 * lane + 1;
    const int lo = row_ptr[node];
    const int jlo = max(lo, c0), jhi = min(lo + hist[node], c1);
    if (ACCUM && jlo >= jhi) return;
    float a0 = 0.f, a1 = 0.f, b0 = 0.f, b1 = 0.f;
    for (int j = jlo; j < jhi; ++j) {
        const uint2 v = *(const uint2*)&MSG[(size_t)(j - c0) * 64 + s0];
        const h16x2 pa = __builtin_bit_cast(h16x2, v.x);
        const h16x2 pb = __builtin_bit_cast(h16x2, v.y);
        a0 += (float)pa.x; a1 += (float)pa.y;
        b0 += (float)pb.x; b1 += (float)pb.y;
    }
    const int cA = (s0 >> 4) * 32 + (s0 & 15);
    const int cB = (s1 >> 4) * 32 + (s1 & 15);
    float* base = &AGG[(size_t)node * 128];
    if (ACCUM) {
        base[cA] += a0; base[cA + 16] += a1;
        base[cB] += b0; base[cB + 16] += b1;
    } else {
        base[cA] = a0; base[cA + 16] = a1;
        base[cB] = b0; base[cB + 16] = b1;
    }
}

extern "C" void kernel_launch(void* const* d_in, const int* in_sizes, int n_in,
                              void* d_out, int out_size, void* d_ws, size_t ws_size,
                              hipStream_t stream) {
    const float* x    = (const float*)d_in[0];
    const float* e    = (const float*)d_in[1];
    const int*   src  = (const int*)  d_in[2];
    const int*   dst  = (const int*)  d_in[3];
    const float* n1W  = (const float*)d_in[4];
    const float* n1b  = (const float*)d_in[5];
    const float* e1W1 = (const float*)d_in[6];
    const float* e1b1 = (const float*)d_in[7];
    const float* e1W2 = (const float*)d_in[8];
    const float* e1b2 = (const float*)d_in[9];
    const float* o1W  = (const float*)d_in[10];
    const float* o1b  = (const float*)d_in[11];
    const float* n2W  = (const float*)d_in[12];
    const float* n2b  = (const float*)d_in[13];
    const float* e2W1 = (const float*)d_in[14];
    const float* e2b1 = (const float*)d_in[15];
    const float* e2W2 = (const float*)d_in[16];
    const float* e2b2 = (const float*)d_in[17];
    const float* o2W  = (const float*)d_in[18];
    const float* o2b  = (const float*)d_in[19];

    const int N = in_sizes[0] / 128;
    const int E = in_sizes[2];
    float* out = (float*)d_out;

    char* ws = (char*)d_ws;
    size_t off = 0;
    auto alloc = [&](size_t bytes) -> char* {
        char* p = ws + off;
        off = (off + bytes + 255) & ~(size_t)255;
        return p;
    };
    float* agg = (float*)alloc((size_t)N * 128 * 4);
    float* hv  = (float*)alloc((size_t)N * 128 * 4);
    unsigned short* w_e1w1 = (unsigned short*)alloc(128 * PK1 * 2);
    unsigned short* w_e1w2 = (unsigned short*)alloc(128 * PK2 * 2);
    unsigned short* w_e2w1 = (unsigned short*)alloc(128 * PK1 * 2);
    unsigned short* w_e2w2 = (unsigned short*)alloc(128 * PK2 * 2);
    unsigned short* n1hi = (unsigned short*)alloc(128 * PK2 * 2);
    unsigned short* n1lo = (unsigned short*)alloc(128 * PK2 * 2);
    unsigned short* o1hi = (unsigned short*)alloc(128 * PK2 * 2);
    unsigned short* o1lo = (unsigned short*)alloc(128 * PK2 * 2);
    unsigned short* n2hi = (unsigned short*)alloc(128 * PK2 * 2);
    unsigned short* n2lo = (unsigned short*)alloc(128 * PK2 * 2);
    unsigned short* o2hi = (unsigned short*)alloc(128 * PK2 * 2);
    unsigned short* o2lo = (unsigned short*)alloc(128 * PK2 * 2);
    int* perm    = (int*)alloc((size_t)E * 4);
    int* srcP    = (int*)alloc((size_t)E * 4);
    int* dstP    = (int*)alloc((size_t)E * 4);
    int* hist    = (int*)alloc((size_t)N * 4);
    int* cursor  = (int*)alloc((size_t)N * 4);
    int* row_ptr = (int*)alloc((size_t)N * 4);
    const size_t sort_need = off;
    unsigned short* Ebf = (unsigned short*)alloc((size_t)E * 64 * 2);
    const bool useEbf  = (ws_size >= off);
    const bool useSort = (ws_size >= sort_need);

    // message-chunk budget (deterministic CSR path), 256 B per packed msg row
    size_t chunkE = 0;
    int nChunks = 0;
    unsigned* msg = nullptr;
    if (useSort && useEbf) {
        size_t budget = (ws_size > off) ? (ws_size - off) : 0;
        size_t rows = (budget / 256) & ~(size_t)63;
        if (rows > (size_t)E) rows = ((size_t)E + 63) & ~(size_t)63;
        if (rows >= 4096) {
            chunkE = rows;
            nChunks = (int)((E + chunkE - 1) / chunkE);
            if (nChunks <= 40) msg = (unsigned*)alloc(chunkE * 256);
            else { chunkE = 0; nChunks = 0; }
        }
    }
    const bool useStore = (msg != nullptr);

    convert_all<<<544, 256, 0, stream>>>(
        e1W1, e1W2, e2W1, e2W2, n1W, o1W, n2W, o2W,
        w_e1w1, w_e1w2, w_e2w1, w_e2w2,
        n1hi, n1lo, o1hi, o1lo, n2hi, n2lo, o2hi, o2lo);

    const int* sA = src;
    const int* dA = dst;
    const int* permArg = nullptr;
    if (useSort) {
        hipMemsetAsync(hist, 0, (size_t)N * 4, stream);
        hist_kernel<<<(E + 255)/256, 256, 0, stream>>>(dst, hist, E);
        scan_kernel<<<1, 1024, 0, stream>>>(hist, row_ptr, cursor, N);
        scatter_kernel<<<(E + 255)/256, 256, 0, stream>>>(dst, cursor, perm, E);
        sort_buckets<<<(N + 255)/256, 256, 0, stream>>>(row_ptr, hist, perm, N);
        if (useEbf) {
            permute_all<<<(int)(((size_t)E * 16 + 255)/256), 256, 0, stream>>>(
                perm, src, dst, e, srcP, dstP, Ebf, E);
        } else {
            permute_sd<<<(E + 255)/256, 256, 0, stream>>>(perm, src, dst, srcP, dstP, E);
        }
        sA = srcP; dA = dstP; permArg = perm;
    }

    const int nodeBlocks = (N + 31) / 32;
    const int gatherBlocks = (N + 7) / 8;
    const size_t nbytes = (size_t)N * 128 * 4;

    auto run_edge_layer = [&](const unsigned short* W1T, const float* b1,
                              const unsigned short* W2T, const float* b2) {
        if (useStore) {
            if (nChunks == 1) {
                edge_mfma<0, 0><<<(E + 63)/64, 256, 0, stream>>>(
                    Ebf, nullptr, nullptr, sA, dA, hv, W1T, b1, W2T, b2, (float*)msg, 0, E);
                gather_kernel<0><<<gatherBlocks, 256, 0, stream>>>(
                    msg, row_ptr, hist, agg, N, 0, E);
            } else {
                hipMemsetAsync(agg, 0, nbytes, stream);
                for (int k = 0; k < nChunks; ++k) {
                    const int c0 = (int)(k * chunkE);
                    const int c1 = (int)min((size_t)E, c0 + chunkE);
                    const int blocks = (c1 - c0 + 63) / 64;
                    edge_mfma<0, 0><<<blocks, 256, 0, stream>>>(
                        Ebf, nullptr, nullptr, sA, dA, hv, W1T, b1, W2T, b2, (float*)msg, c0, c1);
                    gather_kernel<1><<<gatherBlocks, 256, 0, stream>>>(
                        msg, row_ptr, hist, agg, N, c0, c1);
                }
            }
        } else if (useEbf) {
            hipMemsetAsync(agg, 0, nbytes, stream);
            edge_mfma<0, 1><<<(E + 63)/64, 256, 0, stream>>>(
                Ebf, nullptr, nullptr, sA, dA, hv, W1T, b1, W2T, b2, agg, 0, E);
        } else {
            hipMemsetAsync(agg, 0, nbytes, stream);
            edge_mfma<1, 1><<<(E + 63)/64, 256, 0, stream>>>(
                nullptr, e, permArg, sA, dA, hv, W1T, b1, W2T, b2, agg, 0, E);
        }
    };

    // ---- layer 1 ----
    node_mfma3<0><<<nodeBlocks, 256, 0, stream>>>(x, n1hi, n1lo, n1b, hv, N);
    run_edge_layer(w_e1w1, e1b1, w_e1w2, e1b2);

    // ---- fused middle ----
    node_mid<<<nodeBlocks, 256, 0, stream>>>(agg, o1hi, o1lo, o1b, n2hi, n2lo, n2b, hv, N);

    // ---- layer 2 ----
    run_edge_layer(w_e2w1, e2b1, w_e2w2, e2b2);
    node_mfma3<1><<<nodeBlocks, 256, 0, stream>>>(agg, o2hi, o2lo, o2b, out, N);
}

// Round 19
// 661.858 us; speedup vs baseline: 1.1077x; 1.0037x over previous
//
#include <hip/hip_runtime.h>
#include <hip/hip_bf16.h>
#include <math.h>

typedef __bf16 bf16x8 __attribute__((ext_vector_type(8)));
typedef float f32x4 __attribute__((ext_vector_type(4)));
typedef _Float16 h16x2 __attribute__((ext_vector_type(2)));

#define LOG2F 0.6931471805599453f
#define PK1 72     // padded row length (bf16) for K=64 tiles
#define PK2 136    // padded row length (bf16) for K=128 tiles

// shifted softplus: ssp(x) = log(1+e^x) - log2 = max(x,0) + log(0.5 + 0.5*e^(-|x|))
// (log2 folded into the log argument: one v_fma with inline 0.5 consts; 7 VALU ops)
__device__ __forceinline__ float sspf(float x) {
    float t = __expf(-fabsf(x));
    return fmaxf(x, 0.0f) + __logf(fmaf(0.5f, t, 0.5f));
}
__device__ __forceinline__ unsigned short f2bf(float f) {
    union { float f; unsigned u; } v; v.f = f;
    unsigned r = v.u + 0x7FFF + ((v.u >> 16) & 1);
    return (unsigned short)(r >> 16);
}
__device__ __forceinline__ float bf2f(unsigned short u) {
    union { unsigned u; float f; } v; v.u = ((unsigned)u) << 16;
    return v.f;
}
__device__ __forceinline__ unsigned short f2bf_fast(float f) {
    __bf16 h = (__bf16)f;
    return __builtin_bit_cast(unsigned short, h);
}

// ---------------- all weight pre-converts in one kernel ----------------
__global__ void convert_all(
    const float* __restrict__ A0, const float* __restrict__ A1,
    const float* __restrict__ A2, const float* __restrict__ A3,
    const float* __restrict__ A4, const float* __restrict__ A5,
    const float* __restrict__ A6, const float* __restrict__ A7,
    unsigned short* __restrict__ O0, unsigned short* __restrict__ O1,
    unsigned short* __restrict__ O2, unsigned short* __restrict__ O3,
    unsigned short* __restrict__ H4, unsigned short* __restrict__ L4,
    unsigned short* __restrict__ H5, unsigned short* __restrict__ L5,
    unsigned short* __restrict__ H6, unsigned short* __restrict__ L6,
    unsigned short* __restrict__ H7, unsigned short* __restrict__ L7)
{
    const int seg = blockIdx.x / 68;
    const int idx = (blockIdx.x % 68) * 256 + threadIdx.x;
    if (seg < 4) {
        const int PK = (seg == 0 || seg == 2) ? PK1 : PK2;
        const int K  = (seg == 0 || seg == 2) ? 64 : 128;
        if (idx >= 128 * PK) return;
        const float* W = (seg == 0) ? A0 : (seg == 1) ? A1 : (seg == 2) ? A2 : A3;
        unsigned short* O = (seg == 0) ? O0 : (seg == 1) ? O1 : (seg == 2) ? O2 : O3;
        int n = idx / PK, k = idx - n * PK;
        O[idx] = (k < K) ? f2bf(W[k * 128 + n]) : (unsigned short)0;
    } else {
        if (idx >= 128 * PK2) return;
        const float* W = (seg == 4) ? A4 : (seg == 5) ? A5 : (seg == 6) ? A6 : A7;
        unsigned short* H = (seg == 4) ? H4 : (seg == 5) ? H5 : (seg == 6) ? H6 : H7;
        unsigned short* L = (seg == 4) ? L4 : (seg == 5) ? L5 : (seg == 6) ? L6 : L7;
        int n = idx / PK2, k = idx - n * PK2;
        unsigned short h = 0, lo = 0;
        if (k < 128) {
            float w = W[k * 128 + n];
            h = f2bf(w);
            lo = f2bf(w - bf2f(h));
        }
        H[idx] = h; L[idx] = lo;
    }
}

// ---------------- deterministic counting sort by dst ----------------
__global__ void hist_kernel(const int* __restrict__ dst, int* __restrict__ hist, int E) {
    int i = blockIdx.x * 256 + threadIdx.x;
    if (i < E) atomicAdd(&hist[dst[i]], 1);
}
__global__ void scan_kernel(const int* __restrict__ hist, int* __restrict__ row_ptr,
                            int* __restrict__ cursor, int N) {
    __shared__ int part[1024];
    const int tid = threadIdx.x;
    const int chunk = (N + 1023) / 1024;
    const int lo = min(tid * chunk, N);
    const int hi = min(lo + chunk, N);
    int s = 0;
    for (int i = lo; i < hi; ++i) s += hist[i];
    part[tid] = s;
    __syncthreads();
    // Hillis-Steele inclusive scan over 1024 partials
    for (int d = 1; d < 1024; d <<= 1) {
        int t = (tid >= d) ? part[tid - d] : 0;
        __syncthreads();
        part[tid] += t;
        __syncthreads();
    }
    int run = part[tid] - s;   // exclusive prefix for this thread's chunk
    for (int i = lo; i < hi; ++i) { row_ptr[i] = run; cursor[i] = run; run += hist[i]; }
}
__global__ void scatter_kernel(const int* __restrict__ dst, int* __restrict__ cursor,
                               int* __restrict__ perm, int E) {
    int i = blockIdx.x * 256 + threadIdx.x;
    if (i < E) { int p = atomicAdd(&cursor[dst[i]], 1); perm[p] = i; }
}
__global__ void sort_buckets(const int* __restrict__ row_ptr, const int* __restrict__ hist,
                             int* __restrict__ perm, int N) {
    int n = blockIdx.x * 256 + threadIdx.x;
    if (n >= N) return;
    const int lo = row_ptr[n], hi = lo + hist[n];
    for (int i = lo + 1; i < hi; ++i) {
        int v = perm[i]; int j = i - 1;
        while (j >= lo && perm[j] > v) { perm[j + 1] = perm[j]; --j; }
        perm[j + 1] = v;
    }
}
__global__ void permute_sd(const int* __restrict__ perm, const int* __restrict__ src,
                           const int* __restrict__ dst, int* __restrict__ srcP,
                           int* __restrict__ dstP, int E) {
    int i = blockIdx.x * 256 + threadIdx.x;
    if (i < E) { int e = perm[i]; srcP[i] = src[e]; dstP[i] = dst[e]; }
}
__global__ void permute_all(const int* __restrict__ perm, const int* __restrict__ src,
                            const int* __restrict__ dst, const float* __restrict__ Ef,
                            int* __restrict__ srcP, int* __restrict__ dstP,
                            unsigned short* __restrict__ Ebf, int nE) {
    long long idx = (long long)blockIdx.x * 256 + threadIdx.x;
    if (idx >= (long long)nE * 16) return;
    int p = (int)(idx >> 4), q = (int)(idx & 15);
    int e = perm[p];
    if (q == 0) { srcP[p] = src[e]; dstP[p] = dst[e]; }
    float4 v = *(const float4*)&Ef[(size_t)e * 64 + q * 4];
    unsigned short* o = &Ebf[(size_t)p * 64 + q * 4];
    o[0] = f2bf_fast(v.x); o[1] = f2bf_fast(v.y);
    o[2] = f2bf_fast(v.z); o[3] = f2bf_fast(v.w);
}

// ---------------- node GEMM via split-bf16 MFMA (f32-accurate) ----------------
template<int ACT>
__global__ __launch_bounds__(256) void node_mfma3(
    const float* __restrict__ X, const unsigned short* __restrict__ WThi,
    const unsigned short* __restrict__ WTlo, const float* __restrict__ b,
    float* __restrict__ Y, int N)
{
    __shared__ unsigned short sHi[32 * PK2];
    __shared__ unsigned short sLo[32 * PK2];
    const int tid = threadIdx.x;
    const int r0 = blockIdx.x * 32;
    {
        const int r = tid >> 3, c0 = (tid & 7) * 16;
        const int row = min(r0 + r, N - 1);
        const float4* s4 = (const float4*)&X[(size_t)row * 128 + c0];
        unsigned short* dh = &sHi[r * PK2 + c0];
        unsigned short* dl = &sLo[r * PK2 + c0];
#pragma unroll
        for (int j = 0; j < 4; ++j) {
            float4 v = s4[j];
            float c[4] = { v.x, v.y, v.z, v.w };
#pragma unroll
            for (int q = 0; q < 4; ++q) {
                unsigned short h = f2bf_fast(c[q]);
                dh[j * 4 + q] = h;
                dl[j * 4 + q] = f2bf_fast(c[q] - bf2f(h));
            }
        }
    }
    __syncthreads();
    const int w = tid >> 6, l = tid & 63, cb = w * 32, lr = l & 15, hi4 = l >> 4, lk = hi4 * 8;
    const float bb[2] = { b[cb + lr], b[cb + 16 + lr] };
    f32x4 acc[2][2];
#pragma unroll
    for (int mt = 0; mt < 2; ++mt)
#pragma unroll
        for (int nt = 0; nt < 2; ++nt)
            acc[mt][nt] = (f32x4){bb[nt], bb[nt], bb[nt], bb[nt]};
    bf16x8 Bh[2][4], Bl[2][4];
#pragma unroll
    for (int nt = 0; nt < 2; ++nt)
#pragma unroll
        for (int kt = 0; kt < 4; ++kt) {
            Bh[nt][kt] = *(const bf16x8*)&WThi[(size_t)(cb + nt*16 + lr) * PK2 + kt*32 + lk];
            Bl[nt][kt] = *(const bf16x8*)&WTlo[(size_t)(cb + nt*16 + lr) * PK2 + kt*32 + lk];
        }
#pragma unroll
    for (int kt = 0; kt < 4; ++kt)
#pragma unroll
        for (int mt = 0; mt < 2; ++mt) {
            bf16x8 Ah = *(const bf16x8*)&sHi[(mt*16 + lr) * PK2 + kt*32 + lk];
            bf16x8 Al = *(const bf16x8*)&sLo[(mt*16 + lr) * PK2 + kt*32 + lk];
#pragma unroll
            for (int nt = 0; nt < 2; ++nt) {
                acc[mt][nt] = __builtin_amdgcn_mfma_f32_16x16x32_bf16(Ah, Bh[nt][kt], acc[mt][nt], 0, 0, 0);
                acc[mt][nt] = __builtin_amdgcn_mfma_f32_16x16x32_bf16(Al, Bh[nt][kt], acc[mt][nt], 0, 0, 0);
                acc[mt][nt] = __builtin_amdgcn_mfma_f32_16x16x32_bf16(Ah, Bl[nt][kt], acc[mt][nt], 0, 0, 0);
            }
        }
#pragma unroll
    for (int mt = 0; mt < 2; ++mt)
#pragma unroll
        for (int nt = 0; nt < 2; ++nt) {
            const int col = cb + nt*16 + lr;
#pragma unroll
            for (int r = 0; r < 4; ++r) {
                const int row = r0 + mt*16 + hi4*4 + r;
                if (row < N) {
                    float v = acc[mt][nt][r];
                    if (ACT) v = tanhf(sspf(v));
                    Y[(size_t)row * 128 + col] = v;
                }
            }
        }
}

// ---------------- fused middle: HVout = tanh(ssp(AGG@o1W+o1b)) @ n2W + n2b ----------------
__global__ __launch_bounds__(256) void node_mid(
    const float* __restrict__ AGG,
    const unsigned short* __restrict__ W1hi, const unsigned short* __restrict__ W1lo,
    const float* __restrict__ b1,
    const unsigned short* __restrict__ W2hi, const unsigned short* __restrict__ W2lo,
    const float* __restrict__ b2,
    float* __restrict__ HVout, int N)
{
    __shared__ unsigned short sHi[32 * PK2];
    __shared__ unsigned short sLo[32 * PK2];
    const int tid = threadIdx.x;
    const int r0 = blockIdx.x * 32;
    {
        const int r = tid >> 3, c0 = (tid & 7) * 16;
        const int row = min(r0 + r, N - 1);
        const float4* s4 = (const float4*)&AGG[(size_t)row * 128 + c0];
        unsigned short* dh = &sHi[r * PK2 + c0];
        unsigned short* dl = &sLo[r * PK2 + c0];
#pragma unroll
        for (int j = 0; j < 4; ++j) {
            float4 v = s4[j];
            float c[4] = { v.x, v.y, v.z, v.w };
#pragma unroll
            for (int q = 0; q < 4; ++q) {
                unsigned short h = f2bf_fast(c[q]);
                dh[j * 4 + q] = h;
                dl[j * 4 + q] = f2bf_fast(c[q] - bf2f(h));
            }
        }
    }
    __syncthreads();
    const int w = tid >> 6, l = tid & 63, cb = w * 32, lr = l & 15, hi4 = l >> 4, lk = hi4 * 8;

    f32x4 acc1[2][2];
    {
        const float bb[2] = { b1[cb + lr], b1[cb + 16 + lr] };
#pragma unroll
        for (int mt = 0; mt < 2; ++mt)
#pragma unroll
            for (int nt = 0; nt < 2; ++nt)
                acc1[mt][nt] = (f32x4){bb[nt], bb[nt], bb[nt], bb[nt]};
        bf16x8 Bh[2][4], Bl[2][4];
#pragma unroll
        for (int nt = 0; nt < 2; ++nt)
#pragma unroll
            for (int kt = 0; kt < 4; ++kt) {
                Bh[nt][kt] = *(const bf16x8*)&W1hi[(size_t)(cb + nt*16 + lr) * PK2 + kt*32 + lk];
                Bl[nt][kt] = *(const bf16x8*)&W1lo[(size_t)(cb + nt*16 + lr) * PK2 + kt*32 + lk];
            }
#pragma unroll
        for (int kt = 0; kt < 4; ++kt)
#pragma unroll
            for (int mt = 0; mt < 2; ++mt) {
                bf16x8 Ah = *(const bf16x8*)&sHi[(mt*16 + lr) * PK2 + kt*32 + lk];
                bf16x8 Al = *(const bf16x8*)&sLo[(mt*16 + lr) * PK2 + kt*32 + lk];
#pragma unroll
                for (int nt = 0; nt < 2; ++nt) {
                    acc1[mt][nt] = __builtin_amdgcn_mfma_f32_16x16x32_bf16(Ah, Bh[nt][kt], acc1[mt][nt], 0, 0, 0);
                    acc1[mt][nt] = __builtin_amdgcn_mfma_f32_16x16x32_bf16(Al, Bh[nt][kt], acc1[mt][nt], 0, 0, 0);
                    acc1[mt][nt] = __builtin_amdgcn_mfma_f32_16x16x32_bf16(Ah, Bl[nt][kt], acc1[mt][nt], 0, 0, 0);
                }
            }
    }
    __syncthreads();
#pragma unroll
    for (int mt = 0; mt < 2; ++mt)
#pragma unroll
        for (int nt = 0; nt < 2; ++nt) {
            const int col = cb + nt*16 + lr;
#pragma unroll
            for (int r = 0; r < 4; ++r) {
                const int row = mt*16 + hi4*4 + r;
                float v = tanhf(sspf(acc1[mt][nt][r]));
                unsigned short h = f2bf_fast(v);
                sHi[row * PK2 + col] = h;
                sLo[row * PK2 + col] = f2bf_fast(v - bf2f(h));
            }
        }
    __syncthreads();

    f32x4 acc2[2][2];
    {
        const float bb[2] = { b2[cb + lr], b2[cb + 16 + lr] };
#pragma unroll
        for (int mt = 0; mt < 2; ++mt)
#pragma unroll
            for (int nt = 0; nt < 2; ++nt)
                acc2[mt][nt] = (f32x4){bb[nt], bb[nt], bb[nt], bb[nt]};
        bf16x8 Bh[2][4], Bl[2][4];
#pragma unroll
        for (int nt = 0; nt < 2; ++nt)
#pragma unroll
            for (int kt = 0; kt < 4; ++kt) {
                Bh[nt][kt] = *(const bf16x8*)&W2hi[(size_t)(cb + nt*16 + lr) * PK2 + kt*32 + lk];
                Bl[nt][kt] = *(const bf16x8*)&W2lo[(size_t)(cb + nt*16 + lr) * PK2 + kt*32 + lk];
            }
#pragma unroll
        for (int kt = 0; kt < 4; ++kt)
#pragma unroll
            for (int mt = 0; mt < 2; ++mt) {
                bf16x8 Ah = *(const bf16x8*)&sHi[(mt*16 + lr) * PK2 + kt*32 + lk];
                bf16x8 Al = *(const bf16x8*)&sLo[(mt*16 + lr) * PK2 + kt*32 + lk];
#pragma unroll
                for (int nt = 0; nt < 2; ++nt) {
                    acc2[mt][nt] = __builtin_amdgcn_mfma_f32_16x16x32_bf16(Ah, Bh[nt][kt], acc2[mt][nt], 0, 0, 0);
                    acc2[mt][nt] = __builtin_amdgcn_mfma_f32_16x16x32_bf16(Al, Bh[nt][kt], acc2[mt][nt], 0, 0, 0);
                    acc2[mt][nt] = __builtin_amdgcn_mfma_f32_16x16x32_bf16(Ah, Bl[nt][kt], acc2[mt][nt], 0, 0, 0);
                }
            }
    }
#pragma unroll
    for (int mt = 0; mt < 2; ++mt)
#pragma unroll
        for (int nt = 0; nt < 2; ++nt) {
            const int col = cb + nt*16 + lr;
#pragma unroll
            for (int r = 0; r < 4; ++r) {
                const int row = r0 + mt*16 + hi4*4 + r;
                if (row < N) HVout[(size_t)row * 128 + col] = acc2[mt][nt][r];
            }
        }
}

// ---------------- fused edge MLP + gather/filter ----------------
// EPI 0: store packed f16 msg pairs to MSG chunk (deterministic CSR path).
//        slot layout: row*64 + w*16 + lr holds half2{m(col), m(col+16)}, col = w*32+lr.
// EPI 1: per-element f32 atomicAdd into AGG (stable fallback).
template<int MODE, int EPI>
__global__ __launch_bounds__(256) void edge_mfma(
    const unsigned short* __restrict__ Ebf, const float* __restrict__ Ef,
    const int* __restrict__ perm,
    const int* __restrict__ srcA, const int* __restrict__ dstA,
    const float* __restrict__ HV,
    const unsigned short* __restrict__ W1T, const float* __restrict__ b1,
    const unsigned short* __restrict__ W2T, const float* __restrict__ b2,
    float* __restrict__ OUTP, int c0, int c1)
{
    __shared__ unsigned short sT1[64 * PK2];
    __shared__ int sSrc[64], sDst[64];
    __shared__ unsigned short sE[(MODE == 1) ? 64 * PK1 : 4];

    const int tid = threadIdx.x;
    const int e0 = c0 + blockIdx.x * 64;

    if (tid < 64) {
        int gi = min(e0 + tid, c1 - 1);
        sSrc[tid] = srcA[gi];
        if (EPI == 1) sDst[tid] = dstA[gi];
    }
    if (MODE == 1) {
        const int r = tid >> 2, cc0 = (tid & 3) * 16;
        int gi = e0 + r;
        int e = (gi < c1) ? (perm ? perm[gi] : gi) : 0;
        const float4* s4 = (const float4*)&Ef[(size_t)e * 64 + cc0];
        unsigned short* dr = &sE[r * PK1 + cc0];
#pragma unroll
        for (int j = 0; j < 4; ++j) {
            float4 v = s4[j];
            dr[j*4+0] = f2bf_fast(v.x); dr[j*4+1] = f2bf_fast(v.y);
            dr[j*4+2] = f2bf_fast(v.z); dr[j*4+3] = f2bf_fast(v.w);
        }
    }
    __syncthreads();

    const int w = tid >> 6, l = tid & 63, cb = w * 32, lr = l & 15, hi4 = l >> 4, lk = hi4 * 8;
    const float bb1[2] = { b1[cb + lr], b1[cb + 16 + lr] };
    const float bb2[2] = { b2[cb + lr], b2[cb + 16 + lr] };

    bf16x8 B1[2][2];
#pragma unroll
    for (int nt = 0; nt < 2; ++nt)
#pragma unroll
        for (int kt = 0; kt < 2; ++kt)
            B1[nt][kt] = *(const bf16x8*)&W1T[(size_t)(cb + nt*16 + lr) * PK1 + kt*32 + lk];

    f32x4 acc1[4][2];
#pragma unroll
    for (int mt = 0; mt < 4; ++mt)
#pragma unroll
        for (int nt = 0; nt < 2; ++nt)
            acc1[mt][nt] = (f32x4){bb1[nt], bb1[nt], bb1[nt], bb1[nt]};
#pragma unroll
    for (int kt = 0; kt < 2; ++kt)
#pragma unroll
        for (int mt = 0; mt < 4; ++mt) {
            bf16x8 A;
            if (MODE == 0) {
                const int row = min(e0 + mt*16 + lr, c1 - 1);
                A = *(const bf16x8*)&Ebf[(size_t)row * 64 + kt*32 + lk];
            } else {
                A = *(const bf16x8*)&sE[(mt*16 + lr) * PK1 + kt*32 + lk];
            }
#pragma unroll
            for (int nt = 0; nt < 2; ++nt)
                acc1[mt][nt] = __builtin_amdgcn_mfma_f32_16x16x32_bf16(A, B1[nt][kt], acc1[mt][nt], 0, 0, 0);
        }

#pragma unroll
    for (int mt = 0; mt < 4; ++mt)
#pragma unroll
        for (int nt = 0; nt < 2; ++nt) {
            const int col = cb + nt*16 + lr;
#pragma unroll
            for (int r = 0; r < 4; ++r) {
                const int row = mt*16 + hi4*4 + r;
                sT1[row * PK2 + col] = f2bf_fast(sspf(acc1[mt][nt][r]));
            }
        }
    __syncthreads();

    bf16x8 B2[2][4];
#pragma unroll
    for (int nt = 0; nt < 2; ++nt)
#pragma unroll
        for (int kt = 0; kt < 4; ++kt)
            B2[nt][kt] = *(const bf16x8*)&W2T[(size_t)(cb + nt*16 + lr) * PK2 + kt*32 + lk];

    f32x4 acc2[4][2];
#pragma unroll
    for (int mt = 0; mt < 4; ++mt)
#pragma unroll
        for (int nt = 0; nt < 2; ++nt)
            acc2[mt][nt] = (f32x4){bb2[nt], bb2[nt], bb2[nt], bb2[nt]};
#pragma unroll
    for (int kt = 0; kt < 4; ++kt)
#pragma unroll
        for (int mt = 0; mt < 4; ++mt) {
            bf16x8 A = *(const bf16x8*)&sT1[(mt*16 + lr) * PK2 + kt*32 + lk];
#pragma unroll
            for (int nt = 0; nt < 2; ++nt)
                acc2[mt][nt] = __builtin_amdgcn_mfma_f32_16x16x32_bf16(A, B2[nt][kt], acc2[mt][nt], 0, 0, 0);
        }

    const int col0 = cb + lr, col1 = cb + 16 + lr;
#pragma unroll
    for (int mt = 0; mt < 4; ++mt) {
#pragma unroll
        for (int r = 0; r < 4; ++r) {
            const int row = mt*16 + hi4*4 + r;
            if (e0 + row < c1) {
                const float he0 = sspf(acc2[mt][0][r]);
                const float he1 = sspf(acc2[mt][1][r]);
                const int s = sSrc[row];
                const float m0 = HV[(size_t)s * 128 + col0] * he0;
                const float m1 = HV[(size_t)s * 128 + col1] * he1;
                if (EPI == 0) {
                    h16x2 p; p.x = (_Float16)m0; p.y = (_Float16)m1;
                    ((unsigned*)OUTP)[(size_t)(e0 + row - c0) * 64 + (cb >> 1) + lr] =
                        __builtin_bit_cast(unsigned, p);
                } else {
                    const int d = sDst[row];
                    atomicAdd(&OUTP[(size_t)d * 128 + col0], m0);
                    atomicAdd(&OUTP[(size_t)d * 128 + col1], m1);
                }
            }
        }
    }
}

// ---------------- deterministic CSR segmented sum over packed f16 msgs ----------------
// MSG row: 64 x half2; slot s -> cols (s>>4)*32 + (s&15) and +16.
// ACCUM=0: write agg (covers all nodes incl. empty). ACCUM=1: agg += (chunked).
template<int ACCUM>
__global__ __launch_bounds__(256) void gather_kernel(
    const unsigned* __restrict__ MSG, const int* __restrict__ row_ptr,
    const int* __restrict__ hist, float* __restrict__ AGG, int N, int c0, int c1)
{
    const int node = blockIdx.x * 8 + (threadIdx.x >> 5);
    if (node >= N) return;
    const int lane = threadIdx.x & 31;
    const int s0 = 2 * lane, s1 = 2 * lane + 1;
    const int lo = row_ptr[node];
    const int jlo = max(lo, c0), jhi = min(lo + hist[node], c1);
    if (ACCUM && jlo >= jhi) return;
    float a0 = 0.f, a1 = 0.f, b0 = 0.f, b1 = 0.f;
    for (int j = jlo; j < jhi; ++j) {
        const uint2 v = *(const uint2*)&MSG[(size_t)(j - c0) * 64 + s0];
        const h16x2 pa = __builtin_bit_cast(h16x2, v.x);
        const h16x2 pb = __builtin_bit_cast(h16x2, v.y);
        a0 += (float)pa.x; a1 += (float)pa.y;
        b0 += (float)pb.x; b1 += (float)pb.y;
    }
    const int cA = (s0 >> 4) * 32 + (s0 & 15);
    const int cB = (s1 >> 4) * 32 + (s1 & 15);
    float* base = &AGG[(size_t)node * 128];
    if (ACCUM) {
        base[cA] += a0; base[cA + 16] += a1;
        base[cB] += b0; base[cB + 16] += b1;
    } else {
        base[cA] = a0; base[cA + 16] = a1;
        base[cB] = b0; base[cB + 16] = b1;
    }
}

extern "C" void kernel_launch(void* const* d_in, const int* in_sizes, int n_in,
                              void* d_out, int out_size, void* d_ws, size_t ws_size,
                              hipStream_t stream) {
    const float* x    = (const float*)d_in[0];
    const float* e    = (const float*)d_in[1];
    const int*   src  = (const int*)  d_in[2];
    const int*   dst  = (const int*)  d_in[3];
    const float* n1W  = (const float*)d_in[4];
    const float* n1b  = (const float*)d_in[5];
    const float* e1W1 = (const float*)d_in[6];
    const float* e1b1 = (const float*)d_in[7];
    const float* e1W2 = (const float*)d_in[8];
    const float* e1b2 = (const float*)d_in[9];
    const float* o1W  = (const float*)d_in[10];
    const float* o1b  = (const float*)d_in[11];
    const float* n2W  = (const float*)d_in[12];
    const float* n2b  = (const float*)d_in[13];
    const float* e2W1 = (const float*)d_in[14];
    const float* e2b1 = (const float*)d_in[15];
    const float* e2W2 = (const float*)d_in[16];
    const float* e2b2 = (const float*)d_in[17];
    const float* o2W  = (const float*)d_in[18];
    const float* o2b  = (const float*)d_in[19];

    const int N = in_sizes[0] / 128;
    const int E = in_sizes[2];
    float* out = (float*)d_out;

    char* ws = (char*)d_ws;
    size_t off = 0;
    auto alloc = [&](size_t bytes) -> char* {
        char* p = ws + off;
        off = (off + bytes + 255) & ~(size_t)255;
        return p;
    };
    float* agg = (float*)alloc((size_t)N * 128 * 4);
    float* hv  = (float*)alloc((size_t)N * 128 * 4);
    unsigned short* w_e1w1 = (unsigned short*)alloc(128 * PK1 * 2);
    unsigned short* w_e1w2 = (unsigned short*)alloc(128 * PK2 * 2);
    unsigned short* w_e2w1 = (unsigned short*)alloc(128 * PK1 * 2);
    unsigned short* w_e2w2 = (unsigned short*)alloc(128 * PK2 * 2);
    unsigned short* n1hi = (unsigned short*)alloc(128 * PK2 * 2);
    unsigned short* n1lo = (unsigned short*)alloc(128 * PK2 * 2);
    unsigned short* o1hi = (unsigned short*)alloc(128 * PK2 * 2);
    unsigned short* o1lo = (unsigned short*)alloc(128 * PK2 * 2);
    unsigned short* n2hi = (unsigned short*)alloc(128 * PK2 * 2);
    unsigned short* n2lo = (unsigned short*)alloc(128 * PK2 * 2);
    unsigned short* o2hi = (unsigned short*)alloc(128 * PK2 * 2);
    unsigned short* o2lo = (unsigned short*)alloc(128 * PK2 * 2);
    int* perm    = (int*)alloc((size_t)E * 4);
    int* srcP    = (int*)alloc((size_t)E * 4);
    int* dstP    = (int*)alloc((size_t)E * 4);
    int* hist    = (int*)alloc((size_t)N * 4);
    int* cursor  = (int*)alloc((size_t)N * 4);
    int* row_ptr = (int*)alloc((size_t)N * 4);
    const size_t sort_need = off;
    unsigned short* Ebf = (unsigned short*)alloc((size_t)E * 64 * 2);
    const bool useEbf  = (ws_size >= off);
    const bool useSort = (ws_size >= sort_need);

    // message-chunk budget (deterministic CSR path), 256 B per packed msg row
    size_t chunkE = 0;
    int nChunks = 0;
    unsigned* msg = nullptr;
    if (useSort && useEbf) {
        size_t budget = (ws_size > off) ? (ws_size - off) : 0;
        size_t rows = (budget / 256) & ~(size_t)63;
        if (rows > (size_t)E) rows = ((size_t)E + 63) & ~(size_t)63;
        if (rows >= 4096) {
            chunkE = rows;
            nChunks = (int)((E + chunkE - 1) / chunkE);
            if (nChunks <= 40) msg = (unsigned*)alloc(chunkE * 256);
            else { chunkE = 0; nChunks = 0; }
        }
    }
    const bool useStore = (msg != nullptr);

    convert_all<<<544, 256, 0, stream>>>(
        e1W1, e1W2, e2W1, e2W2, n1W, o1W, n2W, o2W,
        w_e1w1, w_e1w2, w_e2w1, w_e2w2,
        n1hi, n1lo, o1hi, o1lo, n2hi, n2lo, o2hi, o2lo);

    const int* sA = src;
    const int* dA = dst;
    const int* permArg = nullptr;
    if (useSort) {
        hipMemsetAsync(hist, 0, (size_t)N * 4, stream);
        hist_kernel<<<(E + 255)/256, 256, 0, stream>>>(dst, hist, E);
        scan_kernel<<<1, 1024, 0, stream>>>(hist, row_ptr, cursor, N);
        scatter_kernel<<<(E + 255)/256, 256, 0, stream>>>(dst, cursor, perm, E);
        sort_buckets<<<(N + 255)/256, 256, 0, stream>>>(row_ptr, hist, perm, N);
        if (useEbf) {
            permute_all<<<(int)(((size_t)E * 16 + 255)/256), 256, 0, stream>>>(
                perm, src, dst, e, srcP, dstP, Ebf, E);
        } else {
            permute_sd<<<(E + 255)/256, 256, 0, stream>>>(perm, src, dst, srcP, dstP, E);
        }
        sA = srcP; dA = dstP; permArg = perm;
    }

    const int nodeBlocks = (N + 31) / 32;
    const int gatherBlocks = (N + 7) / 8;
    const size_t nbytes = (size_t)N * 128 * 4;

    auto run_edge_layer = [&](const unsigned short* W1T, const float* b1,
                              const unsigned short* W2T, const float* b2) {
        if (useStore) {
            if (nChunks == 1) {
                edge_mfma<0, 0><<<(E + 63)/64, 256, 0, stream>>>(
                    Ebf, nullptr, nullptr, sA, dA, hv, W1T, b1, W2T, b2, (float*)msg, 0, E);
                gather_kernel<0><<<gatherBlocks, 256, 0, stream>>>(
                    msg, row_ptr, hist, agg, N, 0, E);
            } else {
                hipMemsetAsync(agg, 0, nbytes, stream);
                for (int k = 0; k < nChunks; ++k) {
                    const int c0 = (int)(k * chunkE);
                    const int c1 = (int)min((size_t)E, c0 + chunkE);
                    const int blocks = (c1 - c0 + 63) / 64;
                    edge_mfma<0, 0><<<blocks, 256, 0, stream>>>(
                        Ebf, nullptr, nullptr, sA, dA, hv, W1T, b1, W2T, b2, (float*)msg, c0, c1);
                    gather_kernel<1><<<gatherBlocks, 256, 0, stream>>>(
                        msg, row_ptr, hist, agg, N, c0, c1);
                }
            }
        } else if (useEbf) {
            hipMemsetAsync(agg, 0, nbytes, stream);
            edge_mfma<0, 1><<<(E + 63)/64, 256, 0, stream>>>(
                Ebf, nullptr, nullptr, sA, dA, hv, W1T, b1, W2T, b2, agg, 0, E);
        } else {
            hipMemsetAsync(agg, 0, nbytes, stream);
            edge_mfma<1, 1><<<(E + 63)/64, 256, 0, stream>>>(
                nullptr, e, permArg, sA, dA, hv, W1T, b1, W2T, b2, agg, 0, E);
        }
    };

    // ---- layer 1 ----
    node_mfma3<0><<<nodeBlocks, 256, 0, stream>>>(x, n1hi, n1lo, n1b, hv, N);
    run_edge_layer(w_e1w1, e1b1, w_e1w2, e1b2);

    // ---- fused middle ----
    node_mid<<<nodeBlocks, 256, 0, stream>>>(agg, o1hi, o1lo, o1b, n2hi, n2lo, n2b, hv, N);

    // ---- layer 2 ----
    run_edge_layer(w_e2w1, e2b1, w_e2w2, e2b2);
    node_mfma3<1><<<nodeBlocks, 256, 0, stream>>>(agg, o2hi, o2lo, o2b, out, N);
}